// Round 1
// baseline (1833.174 us; speedup 1.0000x reference)
//
#include <hip/hip_runtime.h>
#include <math.h>

#define NN 50000
#define EE 800000
#define INF_ 64
#define HH 128
#define LL 3
#define CC 4
#define KK 32
#define OPS_ 7
#define BB 512
#define OUTD 10
#define DD 1024   // 2*H*(L+1)

// ---------------- lin1 + elu : x[N,64] @ W[64,128] + b, elu ----------------
__global__ __launch_bounds__(256) void k_lin1(const float* __restrict__ x,
                                              const float* __restrict__ W,
                                              const float* __restrict__ b,
                                              float* __restrict__ xout) {
    __shared__ float sW[INF_ * HH];
    __shared__ float sb[HH];
    for (int i = threadIdx.x; i < INF_ * HH; i += 256) sW[i] = W[i];
    if (threadIdx.x < HH) sb[threadIdx.x] = b[threadIdx.x];
    __syncthreads();
    int wave = threadIdx.x >> 6, lane = threadIdx.x & 63;
    int base = blockIdx.x * 64;
    for (int i = 0; i < 16; ++i) {
        int n = base + wave * 16 + i;
        if (n >= NN) break;
        float xv = x[n * INF_ + lane];
        float acc0 = sb[lane], acc1 = sb[lane + 64];
        #pragma unroll 8
        for (int h = 0; h < INF_; ++h) {
            float s = __shfl(xv, h, 64);
            acc0 += s * sW[h * HH + lane];
            acc1 += s * sW[h * HH + lane + 64];
        }
        xout[n * HH + lane]      = acc0 > 0.f ? acc0 : expm1f(acc0);
        xout[n * HH + lane + 64] = acc1 > 0.f ? acc1 : expm1f(acc1);
    }
}

// ---------------- degree count ----------------
__global__ void k_deg(const int* __restrict__ dst, int* __restrict__ deg) {
    int e = blockIdx.x * 256 + threadIdx.x;
    if (e < EE) atomicAdd(&deg[dst[e]], 1);
}

// ---------------- CSR offset alloc (order-free) + degc/dinv ----------------
__global__ void k_alloc(const int* __restrict__ deg, int* __restrict__ off,
                        int* __restrict__ gcount, float* __restrict__ degc,
                        float* __restrict__ dinv) {
    int n = blockIdx.x * 256 + threadIdx.x;
    if (n < NN) {
        int d = deg[n];
        off[n] = atomicAdd(gcount, d);
        float dc = fmaxf((float)d, 1.0f);
        degc[n] = dc;
        dinv[n] = rsqrtf(dc);
    }
}

// ---------------- CSR fill ----------------
__global__ void k_csrfill(const int* __restrict__ src, const int* __restrict__ dst,
                          const int* __restrict__ off, int* __restrict__ cursor,
                          int* __restrict__ csr_src) {
    int e = blockIdx.x * 256 + threadIdx.x;
    if (e < EE) {
        int d = dst[e];
        int p = atomicAdd(&cursor[d], 1);
        csr_src[off[d] + p] = src[e];
    }
}

// ---------------- graph offsets from sorted batch ----------------
__global__ void k_goff(const int* __restrict__ batch, int* __restrict__ goff) {
    int i = blockIdx.x * 256 + threadIdx.x;
    if (i >= NN) return;
    int b = batch[i];
    if (i == 0) { for (int g = 0; g <= b; ++g) goff[g] = 0; }
    else {
        int bp = batch[i - 1];
        for (int g = bp + 1; g <= b; ++g) goff[g] = i;
    }
    if (i == NN - 1) { for (int g = b + 1; g <= BB; ++g) goff[g] = NN; }
}

// ---------------- vn init ----------------
__global__ void k_vninit(const float* __restrict__ vn0, float* __restrict__ vn) {
    int i = blockIdx.x * 256 + threadIdx.x;
    if (i < BB * HH) vn[i] = vn0[i & (HH - 1)];
}

// ---------------- x += vn[batch]; a0x/a1x dot products ----------------
__global__ __launch_bounds__(256) void k_addvn_dots(float* __restrict__ x,
                                                    const float* __restrict__ vn,
                                                    const int* __restrict__ batch,
                                                    const float* __restrict__ att,
                                                    float* __restrict__ a0x,
                                                    float* __restrict__ a1x) {
    int wave = threadIdx.x >> 6, lane = threadIdx.x & 63;
    int n = blockIdx.x * 4 + wave;
    if (n >= NN) return;
    int b = batch[n];
    float v0 = x[n * HH + lane]      + vn[b * HH + lane];
    float v1 = x[n * HH + lane + 64] + vn[b * HH + lane + 64];
    x[n * HH + lane] = v0;
    x[n * HH + lane + 64] = v1;
    float d0 = v0 * att[lane] + v1 * att[lane + 64];
    float d1 = v0 * att[HH + lane] + v1 * att[HH + lane + 64];
    #pragma unroll
    for (int s = 32; s; s >>= 1) { d0 += __shfl_xor(d0, s, 64); d1 += __shfl_xor(d1, s, 64); }
    if (lane == 0) { a0x[n] = d0; a1x[n] = d1; }
}

// ---------------- per-node attention + 3 aggregations (one wave / node) ----
__global__ __launch_bounds__(256) void k_agg(const float* __restrict__ x,
                                             const int* __restrict__ off,
                                             const int* __restrict__ deg,
                                             const int* __restrict__ csr_src,
                                             const float* __restrict__ dinv,
                                             const float* __restrict__ a0x,
                                             const float* __restrict__ a1x,
                                             float* __restrict__ aggS,
                                             float* __restrict__ aggN,
                                             float* __restrict__ aggA) {
    int wave = threadIdx.x >> 6, lane = threadIdx.x & 63;
    int n = blockIdx.x * 4 + wave;
    if (n >= NN) return;
    int s = off[n], e = s + deg[n];
    float a1n = a1x[n];
    float dinvn = dinv[n];
    // pass 1: segment max of leaky_relu scores
    float m = -INFINITY;
    for (int j = s + lane; j < e; j += 64) {
        int ss = csr_src[j];
        float ev = a0x[ss] + a1n;
        ev = ev > 0.f ? ev : 0.2f * ev;
        m = fmaxf(m, ev);
    }
    #pragma unroll
    for (int sh = 32; sh; sh >>= 1) m = fmaxf(m, __shfl_xor(m, sh, 64));
    // pass 2: sum of exp
    float ls = 0.f;
    for (int j = s + lane; j < e; j += 64) {
        int ss = csr_src[j];
        float ev = a0x[ss] + a1n;
        ev = ev > 0.f ? ev : 0.2f * ev;
        ls += expf(ev - m);
    }
    #pragma unroll
    for (int sh = 32; sh; sh >>= 1) ls += __shfl_xor(ls, sh, 64);
    float sinv = 1.f / (ls + 1e-16f);
    // pass 3: feature aggregation; lane owns features 2*lane, 2*lane+1
    float2 as = {0.f, 0.f}, an = {0.f, 0.f}, aa = {0.f, 0.f};
    const float2* x2 = (const float2*)x;
    for (int j0 = s; j0 < e; j0 += 64) {
        int cnt = min(64, e - j0);
        int ss = (lane < cnt) ? csr_src[j0 + lane] : 0;
        float wn = dinv[ss] * dinvn;
        float ev = a0x[ss] + a1n;
        ev = ev > 0.f ? ev : 0.2f * ev;
        float wa = expf(ev - m) * sinv;
        for (int k = 0; k < cnt; ++k) {
            int sid  = __shfl(ss, k, 64);
            float wnk = __shfl(wn, k, 64);
            float wak = __shfl(wa, k, 64);
            float2 xv = x2[sid * 64 + lane];
            as.x += xv.x;        as.y += xv.y;
            an.x += wnk * xv.x;  an.y += wnk * xv.y;
            aa.x += wak * xv.x;  aa.y += wak * xv.y;
        }
    }
    ((float2*)aggS)[n * 64 + lane] = as;
    ((float2*)aggN)[n * 64 + lane] = an;
    ((float2*)aggA)[n * 64 + lane] = aa;
}

// ---------------- op-mix GEMM + LayerNorm + DARTS mix + BN partials --------
// 128-node tile, 256 threads, per-thread 8 nodes x 8 cols register tile.
__global__ __launch_bounds__(256, 2) void k_mix(const float* __restrict__ x,
                                                const float* __restrict__ aggS,
                                                const float* __restrict__ aggN,
                                                const float* __restrict__ aggA,
                                                const float* __restrict__ degc,
                                                const float* __restrict__ Wl,
                                                const float* __restrict__ bl,
                                                const float* __restrict__ lng,
                                                const float* __restrict__ lnb,
                                                const float* __restrict__ al,
                                                float* __restrict__ xnew,
                                                float* __restrict__ bnstat) {
    __shared__ __align__(16) float At[32 * 132];      // [hh][node], stride 132
    __shared__ __align__(16) float sW[32 * 192];      // [hh][col chunks of 8, pad to 12]
    __shared__ float sLNg[HH], sLNb[HH];
    __shared__ float sBops[CC * OPS_ * KK];
    __shared__ float sMix[CC * OPS_];
    __shared__ float sSum[HH], sSq[HH];

    int t = threadIdx.x;
    int base = blockIdx.x * 128;
    if (t < HH) { sLNg[t] = lng[t]; sLNb[t] = lnb[t]; sSum[t] = 0.f; sSq[t] = 0.f; }
    for (int i = t; i < CC * OPS_ * KK; i += 256) sBops[i] = bl[i];
    if (t < CC) {
        float a[OPS_]; float mx = -INFINITY;
        for (int o = 0; o < OPS_; ++o) { a[o] = al[t * OPS_ + o]; mx = fmaxf(mx, a[o]); }
        float ssm = 0.f;
        for (int o = 0; o < OPS_; ++o) { a[o] = expf(a[o] - mx); ssm += a[o]; }
        for (int o = 0; o < OPS_; ++o) sMix[t * OPS_ + o] = a[o] / ssm;
    }

    int colgrp = t & 15;           // 16 col groups of 8 cols
    int rowgrp = t >> 4;           // 16 row groups of 8 nodes
    int col = colgrp * 8;          // global col 0..120
    int c = colgrp >> 2;           // cell 0..3
    int kk = (colgrp & 3) * 8;     // k offset inside cell
    int nbase = base + rowgrp * 8;

    float xacc[8][8];
    #pragma unroll
    for (int i = 0; i < 8; ++i)
        #pragma unroll
        for (int j = 0; j < 8; ++j) xacc[i][j] = 0.f;

    for (int o = 0; o < OPS_; ++o) {
        float y[8][8];
        #pragma unroll
        for (int i = 0; i < 8; ++i)
            #pragma unroll
            for (int j = 0; j < 8; ++j) y[i][j] = 0.f;

        for (int hc = 0; hc < 4; ++hc) {
            int hb = hc * 32;
            __syncthreads();
            // stage A chunk (derive op input on the fly)
            for (int idx = t; idx < 32 * 128; idx += 256) {
                int nl = idx >> 5, hh = idx & 31;
                int n = base + nl; if (n >= NN) n = NN - 1;
                int g = n * HH + hb + hh;
                float v;
                if (o == 0 || o == 5)      v = aggN[g];
                else if (o == 1)           v = x[g] + aggS[g];
                else if (o == 2)           v = aggA[g];
                else if (o == 3)           v = x[g] + aggS[g] / degc[n];
                else if (o == 4)           v = aggS[g] / degc[n];
                else                       v = x[g];
                At[hh * 132 + nl] = v;
            }
            // stage W chunk
            for (int idx = t; idx < 32 * 128; idx += 256) {
                int cc2 = idx & 127, hh = idx >> 7;
                int c2 = cc2 >> 5, kl = cc2 & 31;
                float wv = Wl[((c2 * OPS_ + o) * HH + hb + hh) * KK + kl];
                sW[hh * 192 + (cc2 >> 3) * 12 + (cc2 & 7)] = wv;
            }
            __syncthreads();
            for (int hh = 0; hh < 32; ++hh) {
                const float* ar = &At[hh * 132 + rowgrp * 8];
                const float* wr = &sW[hh * 192 + colgrp * 12];
                float av[8], wv[8];
                float4 tq;
                tq = *(const float4*)(ar);     av[0]=tq.x; av[1]=tq.y; av[2]=tq.z; av[3]=tq.w;
                tq = *(const float4*)(ar + 4); av[4]=tq.x; av[5]=tq.y; av[6]=tq.z; av[7]=tq.w;
                tq = *(const float4*)(wr);     wv[0]=tq.x; wv[1]=tq.y; wv[2]=tq.z; wv[3]=tq.w;
                tq = *(const float4*)(wr + 4); wv[4]=tq.x; wv[5]=tq.y; wv[6]=tq.z; wv[7]=tq.w;
                #pragma unroll
                for (int i = 0; i < 8; ++i)
                    #pragma unroll
                    for (int j = 0; j < 8; ++j)
                        y[i][j] = fmaf(av[i], wv[j], y[i][j]);
            }
        }
        // bias + LayerNorm(K=32) + DARTS mix
        float wmix = sMix[c * OPS_ + o];
        const float* bp = &sBops[(c * OPS_ + o) * KK + kk];
        #pragma unroll
        for (int i = 0; i < 8; ++i) {
            float yy[8]; float s = 0.f, s2 = 0.f;
            #pragma unroll
            for (int j = 0; j < 8; ++j) {
                yy[j] = y[i][j] + bp[j];
                s += yy[j]; s2 += yy[j] * yy[j];
            }
            s += __shfl_xor(s, 1); s2 += __shfl_xor(s2, 1);
            s += __shfl_xor(s, 2); s2 += __shfl_xor(s2, 2);
            float mu = s * 0.03125f;
            float var = fmaxf(s2 * 0.03125f - mu * mu, 0.f);
            float rs = rsqrtf(var + 1e-5f);
            #pragma unroll
            for (int j = 0; j < 8; ++j) {
                float yn = (yy[j] - mu) * rs * sLNg[col + j] + sLNb[col + j];
                xacc[i][j] += wmix * yn;
            }
        }
    }
    __syncthreads();
    float psum[8], psq[8];
    #pragma unroll
    for (int j = 0; j < 8; ++j) { psum[j] = 0.f; psq[j] = 0.f; }
    #pragma unroll
    for (int i = 0; i < 8; ++i) {
        int n = nbase + i;
        if (n < NN) {
            float4 v0 = make_float4(xacc[i][0], xacc[i][1], xacc[i][2], xacc[i][3]);
            float4 v1 = make_float4(xacc[i][4], xacc[i][5], xacc[i][6], xacc[i][7]);
            *(float4*)&xnew[n * HH + col] = v0;
            *(float4*)&xnew[n * HH + col + 4] = v1;
            #pragma unroll
            for (int j = 0; j < 8; ++j) { psum[j] += xacc[i][j]; psq[j] += xacc[i][j] * xacc[i][j]; }
        }
    }
    #pragma unroll
    for (int j = 0; j < 8; ++j) {
        atomicAdd(&sSum[col + j], psum[j]);
        atomicAdd(&sSq[col + j], psq[j]);
    }
    __syncthreads();
    if (t < HH) {
        atomicAdd(&bnstat[t], sSum[t]);
        atomicAdd(&bnstat[HH + t], sSq[t]);
    }
}

// ---------------- BN finalize (scale/shift per feature) ----------------
__global__ void k_bnfin(const float* __restrict__ stat, const float* __restrict__ g,
                        const float* __restrict__ b, float* __restrict__ scsh,
                        float invn, int dim) {
    int t = threadIdx.x;
    if (t < dim) {
        float mean = stat[t] * invn;
        float var = fmaxf(stat[dim + t] * invn - mean * mean, 0.f);
        float sc = g[t] * rsqrtf(var + 1e-5f);
        scsh[t] = sc;
        scsh[dim + t] = b[t] - mean * sc;
    }
}

// ---------------- BN apply + per-graph pool (mean/max) + graph sum --------
__global__ void k_pool(const float* __restrict__ src, const float* __restrict__ scsh,
                       const int* __restrict__ goff, float* __restrict__ xout,
                       float* __restrict__ pooled, float* __restrict__ gsum, int slice) {
    int b = blockIdx.x;
    int f = threadIdx.x;           // 128 threads
    int s = goff[b], e = goff[b + 1];
    float sc = 1.f, sh = 0.f;
    if (scsh) { sc = scsh[f]; sh = scsh[HH + f]; }
    float fs = 0.f, fm = -INFINITY;
    for (int i = s; i < e; ++i) {
        float v = src[i * HH + f] * sc + sh;
        if (xout) xout[i * HH + f] = v;
        fs += v;
        fm = fmaxf(fm, v);
    }
    float cnt = fmaxf((float)(e - s), 1.f);
    pooled[b * DD + slice * HH + f] = fs / cnt;
    pooled[b * DD + 512 + slice * HH + f] = (e > s) ? fm : 0.f;
    if (gsum) gsum[b * HH + f] = fs;
}

// ---------------- virtual-node MLP pieces ----------------
__global__ void k_vn1(const float* __restrict__ gsum, const float* __restrict__ vn,
                      const float* __restrict__ W1, const float* __restrict__ b1,
                      float* __restrict__ h1, float* __restrict__ stat) {
    __shared__ float row[HH];
    int b = blockIdx.x, t = threadIdx.x;   // 256 threads
    if (t < HH) row[t] = gsum[b * HH + t] + vn[b * HH + t];
    __syncthreads();
    float acc = b1[t];
    for (int h = 0; h < HH; ++h) acc += row[h] * W1[h * 2 * HH + t];
    h1[b * 2 * HH + t] = acc;
    atomicAdd(&stat[t], acc);
    atomicAdd(&stat[2 * HH + t], acc * acc);
}

__global__ void k_vn2(const float* __restrict__ h1, const float* __restrict__ scsh1,
                      const float* __restrict__ W2, const float* __restrict__ b2,
                      float* __restrict__ h2, float* __restrict__ stat) {
    __shared__ float row[2 * HH];
    int b = blockIdx.x, t = threadIdx.x;   // 256 threads
    float v = h1[b * 2 * HH + t] * scsh1[t] + scsh1[2 * HH + t];
    row[t] = fmaxf(v, 0.f);
    __syncthreads();
    if (t < HH) {
        float acc = b2[t];
        for (int h = 0; h < 2 * HH; ++h) acc += row[h] * W2[h * HH + t];
        h2[b * HH + t] = acc;
        atomicAdd(&stat[t], acc);
        atomicAdd(&stat[HH + t], acc * acc);
    }
}

__global__ void k_vnout(const float* __restrict__ h2, const float* __restrict__ scsh2,
                        float* __restrict__ vn) {
    int i = blockIdx.x * 256 + threadIdx.x;
    if (i < BB * HH) {
        int f = i & (HH - 1);
        float v = h2[i] * scsh2[f] + scsh2[HH + f];
        vn[i] = fmaxf(v, 0.f);
    }
}

// ---------------- masked head ----------------
__global__ void k_head(const float* __restrict__ pooled, const float* __restrict__ W,
                       const float* __restrict__ bias, const float* __restrict__ mask,
                       float* __restrict__ out) {
    int wave = threadIdx.x >> 6, lane = threadIdx.x & 63;
    int idx = blockIdx.x * 4 + wave;
    if (idx >= BB * OUTD) return;
    int b = idx / OUTD, o = idx % OUTD;
    float acc = 0.f;
    for (int k = lane; k < DD; k += 64)
        acc += pooled[b * DD + k] * W[k * OUTD + o] * mask[k * OUTD + o];
    #pragma unroll
    for (int sh = 32; sh; sh >>= 1) acc += __shfl_xor(acc, sh, 64);
    if (lane == 0) out[idx] = acc + bias[o];
}

extern "C" void kernel_launch(void* const* d_in, const int* in_sizes, int n_in,
                              void* d_out, int out_size, void* d_ws, size_t ws_size,
                              hipStream_t stream) {
    const float* x_in   = (const float*)d_in[0];
    const int*   ei     = (const int*)d_in[1];
    const int*   batch  = (const int*)d_in[2];
    const float* lin1W  = (const float*)d_in[3];
    const float* lin1b  = (const float*)d_in[4];
    const float* vn0    = (const float*)d_in[5];
    const float* Wops   = (const float*)d_in[6];
    const float* bops   = (const float*)d_in[7];
    const float* atta   = (const float*)d_in[8];
    const float* lng    = (const float*)d_in[9];
    const float* lnb    = (const float*)d_in[10];
    const float* bng    = (const float*)d_in[11];
    const float* bnb    = (const float*)d_in[12];
    const float* vnW1   = (const float*)d_in[13];
    const float* vnb1   = (const float*)d_in[14];
    const float* vnbn1g = (const float*)d_in[15];
    const float* vnbn1b = (const float*)d_in[16];
    const float* vnW2   = (const float*)d_in[17];
    const float* vnb2   = (const float*)d_in[18];
    const float* vnbn2g = (const float*)d_in[19];
    const float* vnbn2b = (const float*)d_in[20];
    const float* alphas = (const float*)d_in[21];
    const float* headW  = (const float*)d_in[22];
    const float* headb  = (const float*)d_in[23];
    const float* headm  = (const float*)d_in[24];
    float* out = (float*)d_out;
    const int* src = ei;
    const int* dst = ei + EE;

    // ---- workspace layout (fp32 words) ----
    float* ws = (float*)d_ws;
    size_t p = 0;
    float* xcur    = ws + p; p += (size_t)NN * HH;
    float* xnew    = ws + p; p += (size_t)NN * HH;
    float* aggS    = ws + p; p += (size_t)NN * HH;
    float* aggN    = ws + p; p += (size_t)NN * HH;
    float* aggA    = ws + p; p += (size_t)NN * HH;
    float* a0x     = ws + p; p += NN;
    float* a1x     = ws + p; p += NN;
    float* degc    = ws + p; p += NN;
    float* dinv    = ws + p; p += NN;
    float* vn      = ws + p; p += BB * HH;
    float* gsum    = ws + p; p += BB * HH;
    float* h1      = ws + p; p += BB * 2 * HH;
    float* h2      = ws + p; p += BB * HH;
    float* pooled  = ws + p; p += (size_t)BB * DD;
    float* bnscsh  = ws + p; p += LL * 2 * HH;
    float* vnsc1   = ws + p; p += 2 * 2 * (2 * HH);
    float* vnsc2   = ws + p; p += 2 * 2 * HH;
    // zeroed float region (atomic accumulators)
    float* zf = ws + p;
    float* bnstat  = ws + p; p += LL * 2 * HH;          // 768
    float* vnstat1 = ws + p; p += 2 * 2 * (2 * HH);     // 1024
    float* vnstat2 = ws + p; p += 2 * 2 * HH;           // 512
    size_t zf_cnt = (size_t)((ws + p) - zf);
    // int region
    int* ib = (int*)(ws + p);
    int* deg    = ib;                 // zeroed
    int* gcount = ib + NN;            // zeroed
    int* cursor = ib + NN + 1;        // zeroed
    size_t zi_cnt = (size_t)(2 * NN + 1);
    int* off    = ib + 2 * NN + 1;
    int* goff   = off + NN;
    int* csr    = goff + (BB + 1);

    hipMemsetAsync(zf, 0, zf_cnt * sizeof(float), stream);
    hipMemsetAsync(ib, 0, zi_cnt * sizeof(int), stream);

    // ---- graph/CSR setup ----
    k_lin1<<<(NN + 63) / 64, 256, 0, stream>>>(x_in, lin1W, lin1b, xcur);
    k_deg<<<(EE + 255) / 256, 256, 0, stream>>>(dst, deg);
    k_alloc<<<(NN + 255) / 256, 256, 0, stream>>>(deg, off, gcount, degc, dinv);
    k_csrfill<<<(EE + 255) / 256, 256, 0, stream>>>(src, dst, off, cursor, csr);
    k_goff<<<(NN + 255) / 256, 256, 0, stream>>>(batch, goff);
    k_vninit<<<(BB * HH + 255) / 256, 256, 0, stream>>>(vn0, vn);
    // pool slice 0 (gr[0] = elu(lin1) x, pre-vn)
    k_pool<<<BB, HH, 0, stream>>>(xcur, nullptr, goff, nullptr, pooled, nullptr, 0);

    for (int l = 0; l < LL; ++l) {
        k_addvn_dots<<<NN / 4, 256, 0, stream>>>(xcur, vn, batch, atta + l * 2 * HH, a0x, a1x);
        k_agg<<<NN / 4, 256, 0, stream>>>(xcur, off, deg, csr, dinv, a0x, a1x, aggS, aggN, aggA);
        k_mix<<<(NN + 127) / 128, 256, 0, stream>>>(xcur, aggS, aggN, aggA, degc,
                                                    Wops + (size_t)l * CC * OPS_ * HH * KK,
                                                    bops + (size_t)l * CC * OPS_ * KK,
                                                    lng + l * CC * KK, lnb + l * CC * KK,
                                                    alphas + l * CC * OPS_,
                                                    xnew, bnstat + l * 2 * HH);
        k_bnfin<<<1, 128, 0, stream>>>(bnstat + l * 2 * HH, bng + l * HH, bnb + l * HH,
                                       bnscsh + l * 2 * HH, 1.0f / (float)NN, HH);
        k_pool<<<BB, HH, 0, stream>>>(xnew, bnscsh + l * 2 * HH, goff, xcur, pooled,
                                      (l < LL - 1) ? gsum : nullptr, l + 1);
        if (l < LL - 1) {
            k_vn1<<<BB, 256, 0, stream>>>(gsum, vn, vnW1 + (size_t)l * HH * 2 * HH,
                                          vnb1 + l * 2 * HH, h1, vnstat1 + l * 2 * (2 * HH));
            k_bnfin<<<1, 256, 0, stream>>>(vnstat1 + l * 2 * (2 * HH), vnbn1g + l * 2 * HH,
                                           vnbn1b + l * 2 * HH, vnsc1 + l * 2 * (2 * HH),
                                           1.0f / (float)BB, 2 * HH);
            k_vn2<<<BB, 256, 0, stream>>>(h1, vnsc1 + l * 2 * (2 * HH),
                                          vnW2 + (size_t)l * 2 * HH * HH, vnb2 + l * HH,
                                          h2, vnstat2 + l * 2 * HH);
            k_bnfin<<<1, 128, 0, stream>>>(vnstat2 + l * 2 * HH, vnbn2g + l * HH,
                                           vnbn2b + l * HH, vnsc2 + l * 2 * HH,
                                           1.0f / (float)BB, HH);
            k_vnout<<<(BB * HH + 255) / 256, 256, 0, stream>>>(h2, vnsc2 + l * 2 * HH, vn);
        }
    }
    k_head<<<(BB * OUTD) / 4, 256, 0, stream>>>(pooled, headW, headb, headm, out);
}